// Round 2
// baseline (1168.971 us; speedup 1.0000x reference)
//
#include <hip/hip_runtime.h>
#include <hip/hip_bf16.h>
#include <math.h>
#include <stdint.h>

#define HH 768
#define TT 32
#define KK 832           // H + 2T
#define SS 2048
#define NSTEP 26         // KK / 32
#define NTOK 65536       // B*S

typedef __attribute__((ext_vector_type(4))) float f32x4;
typedef __attribute__((ext_vector_type(8))) short bf16x8;
typedef __attribute__((ext_vector_type(4))) short bf16x4;

__device__ __forceinline__ short f2bf(float f) {
  union { float f; uint32_t u; } v; v.f = f;
  uint32_t u = v.u;
  return (short)((u + 0x7FFFu + ((u >> 16) & 1u)) >> 16);
}

// ---------------- transpose lin_W -> Btw[n][k] bf16 ----------------
__global__ void transpose_w_kernel(const float* __restrict__ lin_W,
                                   short* __restrict__ bt) {
  int i = blockIdx.x * 256 + threadIdx.x;
  if (i >= HH * KK) return;
  int n = i / KK;
  int k = i - n * KK;
  bt[i] = f2bf(lin_W[(size_t)k * HH + n]);
}

// ------------- gather kernel: build A[65536][832] bf16 -------------
// one wave per token; contiguous 3KB word-row read + fused sinusoids
__global__ __launch_bounds__(256) void gather_a_kernel(
    const int* __restrict__ input_ids, const float* __restrict__ ts,
    const float* __restrict__ ages, const float* __restrict__ W_word,
    const float* __restrict__ time_w, const float* __restrict__ time_phi,
    const float* __restrict__ age_w, const float* __restrict__ age_phi,
    short* __restrict__ Aws) {
  const int wave = threadIdx.x >> 6, lane = threadIdx.x & 63;
  const int t = blockIdx.x * 4 + wave;
  if (t >= NTOK) return;
  const float* wrow = W_word + (size_t)input_ids[t] * HH;
  const int s = t & (SS - 1);
  const float dt = (s == 0) ? 0.f : (ts[t] - ts[t - 1]);
  const float age = ages[t];
  short* dst = Aws + (size_t)t * KK;
#pragma unroll
  for (int c2 = 0; c2 < 2; ++c2) {
    int chunk = c2 * 64 + lane;
    if (chunk < 104) {
      int k = chunk * 8;
      bf16x8 v;
      if (k < HH) {
        f32x4 x0 = *(const f32x4*)(wrow + k);
        f32x4 x1 = *(const f32x4*)(wrow + k + 4);
        v[0] = f2bf(x0[0]); v[1] = f2bf(x0[1]); v[2] = f2bf(x0[2]); v[3] = f2bf(x0[3]);
        v[4] = f2bf(x1[0]); v[5] = f2bf(x1[1]); v[6] = f2bf(x1[2]); v[7] = f2bf(x1[3]);
      } else if (k < HH + TT) {
        int j = k - HH;
#pragma unroll
        for (int i = 0; i < 8; ++i)
          v[i] = f2bf(sinf(dt * time_w[j + i] + time_phi[j + i]));
      } else {
        int j = k - HH - TT;
#pragma unroll
        for (int i = 0; i < 8; ++i)
          v[i] = f2bf(sinf(age * age_w[j + i] + age_phi[j + i]));
      }
      *(bf16x8*)(dst + k) = v;
    }
  }
}

// ---------------- main GEMM + epilogue kernel ----------------------
// LDS 16B-unit layouts (conflict-free ds_read_b128):
//   Atile: idx16 = panel*64 + kq*16 + rin   (panel = row>>4, rin = row&15)
//   Bt:    idx16 = (n>>4)*64 + kq*16 + (n&15)
__global__ __launch_bounds__(512, 1) void ehr_gemm_kernel(
    const int* __restrict__ type_ids, const int* __restrict__ visit_orders,
    const int* __restrict__ visit_segments, const float* __restrict__ W_type,
    const float* __restrict__ W_order, const float* __restrict__ W_seg,
    const float* __restrict__ lin_b, const float* __restrict__ ln_g,
    const float* __restrict__ ln_beta, const short* __restrict__ Aws,
    const short* __restrict__ Btw, float* __restrict__ out) {
  __shared__ short Bt[HH * 32];     // 48KB
  __shared__ short Atile[64 * 32];  // 4KB
  __shared__ int tyl[64], orl[64], sgl[64];
  __shared__ float redS[4][64], redQ[4][64];

  const int tid = threadIdx.x;
  const int t0 = blockIdx.x * 64;
  if (tid < 64) {
    tyl[tid] = type_ids[t0 + tid];
    orl[tid] = visit_orders[t0 + tid];
    sgl[tid] = visit_segments[t0 + tid];
  }
  const int lane = tid & 63, wave = tid >> 6;
  const int wm = wave >> 2, wn = wave & 3;
  const int l15 = lane & 15, l4 = lane >> 4;

  f32x4 acc[2][12];
#pragma unroll
  for (int mf = 0; mf < 2; ++mf)
#pragma unroll
    for (int nf = 0; nf < 12; ++nf) acc[mf][nf] = (f32x4)(0.0f);

  // per-lane DMA source bases (lane -> (rin/nin = lane&15, kq = lane>>4))
  const size_t a_lane_off = (size_t)l15 * KK + l4 * 8;

  for (int st = 0; st < NSTEP; ++st) {
    const int k0 = st * 32;
    // A: 4 chunks of 1KB, waves 0..3
    if (wave < 4) {
      const short* src = Aws + (size_t)(t0 + wave * 16) * KK + a_lane_off + k0;
      __builtin_amdgcn_global_load_lds(
          (const __attribute__((address_space(1))) unsigned int*)src,
          (__attribute__((address_space(3))) unsigned int*)(Atile + wave * 512),
          16, 0, 0);
    }
    // B: 48 chunks of 1KB, all waves
#pragma unroll
    for (int p = 0; p < 6; ++p) {
      int c = p * 8 + wave;
      const short* src = Btw + (size_t)(c * 16) * KK + a_lane_off + k0;
      __builtin_amdgcn_global_load_lds(
          (const __attribute__((address_space(1))) unsigned int*)src,
          (__attribute__((address_space(3))) unsigned int*)(Bt + c * 512),
          16, 0, 0);
    }
    __syncthreads();

    const bf16x8* Af = (const bf16x8*)Atile;
    const bf16x8* Bf = (const bf16x8*)Bt;
    bf16x8 a0 = Af[(wm * 2 + 0) * 64 + l4 * 16 + l15];
    bf16x8 a1 = Af[(wm * 2 + 1) * 64 + l4 * 16 + l15];
#pragma unroll
    for (int nf = 0; nf < 12; ++nf) {
      bf16x8 b = Bf[(wn * 12 + nf) * 64 + l4 * 16 + l15];
      acc[0][nf] = __builtin_amdgcn_mfma_f32_16x16x32_bf16(a0, b, acc[0][nf], 0, 0, 0);
      acc[1][nf] = __builtin_amdgcn_mfma_f32_16x16x32_bf16(a1, b, acc[1][nf], 0, 0, 0);
    }
    __syncthreads();
  }

  // ---- epilogue: tanh + embedding adds + LayerNorm stats
  float sp[2][4], sq[2][4];
#pragma unroll
  for (int mf = 0; mf < 2; ++mf)
#pragma unroll
    for (int r = 0; r < 4; ++r) { sp[mf][r] = 0.f; sq[mf][r] = 0.f; }

#pragma unroll
  for (int nf = 0; nf < 12; ++nf) {
    int n = wn * 192 + nf * 16 + l15;
    float bias = lin_b[n];
#pragma unroll
    for (int mf = 0; mf < 2; ++mf) {
#pragma unroll
      for (int r = 0; r < 4; ++r) {
        int row = wm * 32 + mf * 16 + l4 * 4 + r;
        float z = tanhf(acc[mf][nf][r] + bias);
        z += W_type[(size_t)tyl[row] * HH + n];
        z += W_order[(size_t)orl[row] * HH + n];
        z += W_seg[(size_t)sgl[row] * HH + n];
        acc[mf][nf][r] = z;
        sp[mf][r] += z;
        sq[mf][r] += z * z;
      }
    }
  }
#pragma unroll
  for (int m = 1; m < 16; m <<= 1) {
#pragma unroll
    for (int mf = 0; mf < 2; ++mf)
#pragma unroll
      for (int r = 0; r < 4; ++r) {
        sp[mf][r] += __shfl_xor(sp[mf][r], m, 64);
        sq[mf][r] += __shfl_xor(sq[mf][r], m, 64);
      }
  }
  if (l15 == 0) {
#pragma unroll
    for (int mf = 0; mf < 2; ++mf)
#pragma unroll
      for (int r = 0; r < 4; ++r) {
        int row = wm * 32 + mf * 16 + l4 * 4 + r;
        redS[wn][row] = sp[mf][r];
        redQ[wn][row] = sq[mf][r];
      }
  }
  __syncthreads();

  float mu[2][4], rs[2][4];
#pragma unroll
  for (int mf = 0; mf < 2; ++mf)
#pragma unroll
    for (int r = 0; r < 4; ++r) {
      int row = wm * 32 + mf * 16 + l4 * 4 + r;
      float s = redS[0][row] + redS[1][row] + redS[2][row] + redS[3][row];
      float q = redQ[0][row] + redQ[1][row] + redQ[2][row] + redQ[3][row];
      float m_ = s * (1.0f / 768.0f);
      float v_ = q * (1.0f / 768.0f) - m_ * m_;
      if (v_ < 0.f) v_ = 0.f;
      mu[mf][r] = m_;
      rs[mf][r] = rsqrtf(v_ + 1e-12f);
    }

  // ---- staged stores: 4 groups of 16 rows through LDS, contiguous out
  float* Os = (float*)Bt;  // 48KB >= 16*768*4
#pragma unroll 1
  for (int g = 0; g < 4; ++g) {
    int gw = g >> 1, gm = g & 1;
    __syncthreads();
    if (wm == gw) {
#pragma unroll
      for (int nf = 0; nf < 12; ++nf) {
        int n = wn * 192 + nf * 16 + l15;
        float gg = ln_g[n], be = ln_beta[n];
#pragma unroll
        for (int r = 0; r < 4; ++r) {
          int lr = l4 * 4 + r;
          Os[lr * HH + n] = (acc[gm][nf][r] - mu[gm][r]) * rs[gm][r] * gg + be;
        }
      }
    }
    __syncthreads();
    float* ob = out + (size_t)(t0 + g * 16) * HH;
#pragma unroll
    for (int q = 0; q < 6; ++q) {
      int idx4 = q * 512 + tid;
      ((f32x4*)ob)[idx4] = ((const f32x4*)Os)[idx4];
    }
  }
}

// =================== fallback (R1 kernel, ws-light) ===================
template <bool WS>
__global__ __launch_bounds__(512, 1) void ehr_fallback(
    const int* __restrict__ input_ids, const int* __restrict__ type_ids,
    const float* __restrict__ time_stamps, const float* __restrict__ ages,
    const int* __restrict__ visit_orders, const int* __restrict__ visit_segments,
    const float* __restrict__ W_word, const float* __restrict__ W_type,
    const float* __restrict__ W_order, const float* __restrict__ W_seg,
    const float* __restrict__ time_w, const float* __restrict__ time_phi,
    const float* __restrict__ age_w, const float* __restrict__ age_phi,
    const float* __restrict__ lin_W, const float* __restrict__ lin_b,
    const float* __restrict__ ln_g, const float* __restrict__ ln_beta,
    const short* __restrict__ bt_ws, float* __restrict__ out) {
  __shared__ short Bt[HH * 32];
  __shared__ short Atile[64 * 32];
  __shared__ float dtl[64], agel[64];
  __shared__ int idl[64], tyl[64], orl[64], sgl[64];
  __shared__ float tpar[128];
  __shared__ float redS[4][64], redQ[4][64];

  const int tid = threadIdx.x;
  const int t0 = blockIdx.x * 64;

  if (tid < 128) {
    int j = tid & 31;
    float v;
    if (tid < 32) v = time_w[j];
    else if (tid < 64) v = time_phi[j];
    else if (tid < 96) v = age_w[j];
    else v = age_phi[j];
    tpar[tid] = v;
  }
  if (tid < 64) {
    int t = t0 + tid;
    int s = t & (SS - 1);
    float tsv = time_stamps[t];
    dtl[tid] = (s == 0) ? 0.f : (tsv - time_stamps[t - 1]);
    agel[tid] = ages[t];
    idl[tid] = input_ids[t];
    tyl[tid] = type_ids[t];
    orl[tid] = visit_orders[t];
    sgl[tid] = visit_segments[t];
  }
  __syncthreads();

  const int lane = tid & 63, wave = tid >> 6;
  const int wm = wave >> 2, wn = wave & 3;
  const int l15 = lane & 15, l4 = lane >> 4;
  const int arow = tid >> 3, ac = tid & 7;
  const int myid = idl[arow];
  const float mydt = dtl[arow];
  const float myage = agel[arow];
  const float* wrow = W_word + (size_t)myid * HH;

  f32x4 acc[2][12];
#pragma unroll
  for (int mf = 0; mf < 2; ++mf)
#pragma unroll
    for (int nf = 0; nf < 12; ++nf) acc[mf][nf] = (f32x4)(0.0f);

  for (int st = 0; st < NSTEP; ++st) {
    const int k0 = st * 32;
    {
      int kg = k0 + ac * 4;
      bf16x4 w4;
      if (kg < HH) {
        const f32x4 v = *(const f32x4*)(wrow + kg);
        w4[0] = f2bf(v[0]); w4[1] = f2bf(v[1]);
        w4[2] = f2bf(v[2]); w4[3] = f2bf(v[3]);
      } else {
        int isAge = (kg >= HH + TT);
        int j = kg - (isAge ? (HH + TT) : HH);
        float x = isAge ? myage : mydt;
        int wof = isAge ? 64 : 0;
#pragma unroll
        for (int i = 0; i < 4; ++i)
          w4[i] = f2bf(sinf(x * tpar[wof + j + i] + tpar[wof + 32 + j + i]));
      }
      *(bf16x4*)(Atile + tid * 4) = w4;
    }
    if (WS) {
#pragma unroll
      for (int p = 0; p < 6; ++p) {
        int chunk = p * 8 + wave;
        short* ldst = Bt + chunk * 512;
        int n = chunk * 16 + (lane >> 2);
        int q = lane & 3;
        const short* src = bt_ws + (size_t)n * KK + k0 + q * 8;
        __builtin_amdgcn_global_load_lds(
            (const __attribute__((address_space(1))) unsigned int*)src,
            (__attribute__((address_space(3))) unsigned int*)ldst, 16, 0, 0);
      }
    } else {
#pragma unroll
      for (int i6 = 0; i6 < 6; ++i6) {
        int c = i6 * 512 + tid;
        int n = c >> 2, q = c & 3;
        int kb = k0 + q * 8;
        bf16x8 w8;
#pragma unroll
        for (int j = 0; j < 8; ++j) w8[j] = f2bf(lin_W[(size_t)(kb + j) * HH + n]);
        *(bf16x8*)(Bt + n * 32 + q * 8) = w8;
      }
    }
    __syncthreads();

    const bf16x8* Af = (const bf16x8*)Atile;
    const bf16x8* Bf = (const bf16x8*)Bt;
    bf16x8 a0 = Af[(wm * 32 + l15) * 4 + l4];
    bf16x8 a1 = Af[(wm * 32 + 16 + l15) * 4 + l4];
#pragma unroll
    for (int nf = 0; nf < 12; ++nf) {
      int n = wn * 192 + nf * 16 + l15;
      bf16x8 b = Bf[n * 4 + l4];
      acc[0][nf] = __builtin_amdgcn_mfma_f32_16x16x32_bf16(a0, b, acc[0][nf], 0, 0, 0);
      acc[1][nf] = __builtin_amdgcn_mfma_f32_16x16x32_bf16(a1, b, acc[1][nf], 0, 0, 0);
    }
    __syncthreads();
  }

  float sp[2][4], sq[2][4];
#pragma unroll
  for (int mf = 0; mf < 2; ++mf)
#pragma unroll
    for (int r = 0; r < 4; ++r) { sp[mf][r] = 0.f; sq[mf][r] = 0.f; }

#pragma unroll
  for (int nf = 0; nf < 12; ++nf) {
    int n = wn * 192 + nf * 16 + l15;
    float bias = lin_b[n];
#pragma unroll
    for (int mf = 0; mf < 2; ++mf) {
#pragma unroll
      for (int r = 0; r < 4; ++r) {
        int row = wm * 32 + mf * 16 + l4 * 4 + r;
        float z = tanhf(acc[mf][nf][r] + bias);
        z += W_type[(size_t)tyl[row] * HH + n];
        z += W_order[(size_t)orl[row] * HH + n];
        z += W_seg[(size_t)sgl[row] * HH + n];
        acc[mf][nf][r] = z;
        sp[mf][r] += z;
        sq[mf][r] += z * z;
      }
    }
  }
#pragma unroll
  for (int m = 1; m < 16; m <<= 1) {
#pragma unroll
    for (int mf = 0; mf < 2; ++mf)
#pragma unroll
      for (int r = 0; r < 4; ++r) {
        sp[mf][r] += __shfl_xor(sp[mf][r], m, 64);
        sq[mf][r] += __shfl_xor(sq[mf][r], m, 64);
      }
  }
  if (l15 == 0) {
#pragma unroll
    for (int mf = 0; mf < 2; ++mf)
#pragma unroll
      for (int r = 0; r < 4; ++r) {
        int row = wm * 32 + mf * 16 + l4 * 4 + r;
        redS[wn][row] = sp[mf][r];
        redQ[wn][row] = sq[mf][r];
      }
  }
  __syncthreads();

  float mu[2][4], rs[2][4];
#pragma unroll
  for (int mf = 0; mf < 2; ++mf)
#pragma unroll
    for (int r = 0; r < 4; ++r) {
      int row = wm * 32 + mf * 16 + l4 * 4 + r;
      float s = redS[0][row] + redS[1][row] + redS[2][row] + redS[3][row];
      float q = redQ[0][row] + redQ[1][row] + redQ[2][row] + redQ[3][row];
      float m_ = s * (1.0f / 768.0f);
      float v_ = q * (1.0f / 768.0f) - m_ * m_;
      if (v_ < 0.f) v_ = 0.f;
      mu[mf][r] = m_;
      rs[mf][r] = rsqrtf(v_ + 1e-12f);
    }

#pragma unroll
  for (int nf = 0; nf < 12; ++nf) {
    int n = wn * 192 + nf * 16 + l15;
    float g = ln_g[n], be = ln_beta[n];
#pragma unroll
    for (int mf = 0; mf < 2; ++mf) {
#pragma unroll
      for (int r = 0; r < 4; ++r) {
        int row = wm * 32 + mf * 16 + l4 * 4 + r;
        out[(size_t)(t0 + row) * HH + n] =
            (acc[mf][nf][r] - mu[mf][r]) * rs[mf][r] * g + be;
      }
    }
  }
}

extern "C" void kernel_launch(void* const* d_in, const int* in_sizes, int n_in,
                              void* d_out, int out_size, void* d_ws, size_t ws_size,
                              hipStream_t stream) {
  const int* input_ids = (const int*)d_in[0];
  const int* type_ids = (const int*)d_in[1];
  const float* time_stamps = (const float*)d_in[2];
  const float* ages = (const float*)d_in[3];
  const int* visit_orders = (const int*)d_in[4];
  const int* visit_segments = (const int*)d_in[5];
  const float* W_word = (const float*)d_in[6];
  const float* W_type = (const float*)d_in[7];
  const float* W_order = (const float*)d_in[8];
  const float* W_seg = (const float*)d_in[9];
  const float* time_w = (const float*)d_in[10];
  const float* time_phi = (const float*)d_in[11];
  const float* age_w = (const float*)d_in[12];
  const float* age_phi = (const float*)d_in[13];
  const float* lin_W = (const float*)d_in[14];
  const float* lin_b = (const float*)d_in[15];
  const float* ln_g = (const float*)d_in[16];
  const float* ln_beta = (const float*)d_in[17];
  float* out = (float*)d_out;

  const size_t a_bytes = (size_t)NTOK * KK * sizeof(short);   // ~109 MB
  const size_t bt_bytes = (size_t)HH * KK * sizeof(short);    // ~1.2 MB

  if (d_ws != nullptr && ws_size >= a_bytes + bt_bytes) {
    short* Aws = (short*)d_ws;
    short* Btw = (short*)((char*)d_ws + a_bytes);
    transpose_w_kernel<<<dim3((HH * KK + 255) / 256), dim3(256), 0, stream>>>(lin_W, Btw);
    gather_a_kernel<<<dim3(NTOK / 4), dim3(256), 0, stream>>>(
        input_ids, time_stamps, ages, W_word, time_w, time_phi, age_w, age_phi, Aws);
    ehr_gemm_kernel<<<dim3(NTOK / 64), dim3(512), 0, stream>>>(
        type_ids, visit_orders, visit_segments, W_type, W_order, W_seg,
        lin_b, ln_g, ln_beta, (const short*)Aws, (const short*)Btw, out);
  } else if (d_ws != nullptr && ws_size >= bt_bytes) {
    short* bt = (short*)d_ws;
    transpose_w_kernel<<<dim3((HH * KK + 255) / 256), dim3(256), 0, stream>>>(lin_W, bt);
    ehr_fallback<true><<<dim3(1024), dim3(512), 0, stream>>>(
        input_ids, type_ids, time_stamps, ages, visit_orders, visit_segments,
        W_word, W_type, W_order, W_seg, time_w, time_phi, age_w, age_phi,
        lin_W, lin_b, ln_g, ln_beta, (const short*)bt, out);
  } else {
    ehr_fallback<false><<<dim3(1024), dim3(512), 0, stream>>>(
        input_ids, type_ids, time_stamps, ages, visit_orders, visit_segments,
        W_word, W_type, W_order, W_seg, time_w, time_phi, age_w, age_phi,
        lin_W, lin_b, ln_g, ln_beta, nullptr, out);
  }
}

// Round 3
// 763.793 us; speedup vs baseline: 1.5305x; 1.5305x over previous
//
#include <hip/hip_runtime.h>
#include <hip/hip_bf16.h>
#include <math.h>
#include <stdint.h>

#define HH 768
#define TT 32
#define KK 832           // H + 2T
#define SS 2048
#define NSTEP 26         // KK / 32
#define NTOK 65536       // B*S

typedef __attribute__((ext_vector_type(4))) float f32x4;
typedef __attribute__((ext_vector_type(8))) short bf16x8;
typedef __attribute__((ext_vector_type(4))) short bf16x4;

__device__ __forceinline__ short f2bf(float f) {
  union { float f; uint32_t u; } v; v.f = f;
  uint32_t u = v.u;
  return (short)((u + 0x7FFFu + ((u >> 16) & 1u)) >> 16);
}

// ---------------- transpose lin_W -> Btw[n][k] bf16 ----------------
__global__ void transpose_w_kernel(const float* __restrict__ lin_W,
                                   short* __restrict__ bt) {
  int i = blockIdx.x * 256 + threadIdx.x;
  if (i >= HH * KK) return;
  int n = i / KK;
  int k = i - n * KK;
  bt[i] = f2bf(lin_W[(size_t)k * HH + n]);
}

// ------------- gather kernel: build A[65536][832] bf16 -------------
__global__ __launch_bounds__(256) void gather_a_kernel(
    const int* __restrict__ input_ids, const float* __restrict__ ts,
    const float* __restrict__ ages, const float* __restrict__ W_word,
    const float* __restrict__ time_w, const float* __restrict__ time_phi,
    const float* __restrict__ age_w, const float* __restrict__ age_phi,
    short* __restrict__ Aws) {
  const int wave = threadIdx.x >> 6, lane = threadIdx.x & 63;
  const int t = blockIdx.x * 4 + wave;
  if (t >= NTOK) return;
  const float* wrow = W_word + (size_t)input_ids[t] * HH;
  const int s = t & (SS - 1);
  const float dt = (s == 0) ? 0.f : (ts[t] - ts[t - 1]);
  const float age = ages[t];
  short* dst = Aws + (size_t)t * KK;
#pragma unroll
  for (int c2 = 0; c2 < 2; ++c2) {
    int chunk = c2 * 64 + lane;
    if (chunk < 104) {
      int k = chunk * 8;
      bf16x8 v;
      if (k < HH) {
        f32x4 x0 = *(const f32x4*)(wrow + k);
        f32x4 x1 = *(const f32x4*)(wrow + k + 4);
        v[0] = f2bf(x0[0]); v[1] = f2bf(x0[1]); v[2] = f2bf(x0[2]); v[3] = f2bf(x0[3]);
        v[4] = f2bf(x1[0]); v[5] = f2bf(x1[1]); v[6] = f2bf(x1[2]); v[7] = f2bf(x1[3]);
      } else if (k < HH + TT) {
        int j = k - HH;
#pragma unroll
        for (int i = 0; i < 8; ++i)
          v[i] = f2bf(sinf(dt * time_w[j + i] + time_phi[j + i]));
      } else {
        int j = k - HH - TT;
#pragma unroll
        for (int i = 0; i < 8; ++i)
          v[i] = f2bf(sinf(age * age_w[j + i] + age_phi[j + i]));
      }
      *(bf16x8*)(dst + k) = v;
    }
  }
}

// ---------------- main GEMM + epilogue kernel ----------------------
__global__ __launch_bounds__(512, 1) void ehr_gemm_kernel(
    const int* __restrict__ type_ids, const int* __restrict__ visit_orders,
    const int* __restrict__ visit_segments, const float* __restrict__ W_type,
    const float* __restrict__ W_order, const float* __restrict__ W_seg,
    const float* __restrict__ lin_b, const float* __restrict__ ln_g,
    const float* __restrict__ ln_beta, const short* __restrict__ Aws,
    const short* __restrict__ Btw, float* __restrict__ out) {
  __shared__ short Bt[HH * 32];     // 48KB
  __shared__ short Atile[64 * 32];  // 4KB
  __shared__ int tyl[64], orl[64], sgl[64];
  __shared__ float redS[4][64], redQ[4][64];

  const int tid = threadIdx.x;
  const int t0 = blockIdx.x * 64;
  if (tid < 64) {
    tyl[tid] = type_ids[t0 + tid];
    orl[tid] = visit_orders[t0 + tid];
    sgl[tid] = visit_segments[t0 + tid];
  }
  const int lane = tid & 63, wave = tid >> 6;
  const int wm = wave >> 2, wn = wave & 3;
  const int l15 = lane & 15, l4 = lane >> 4;

  f32x4 acc[2][12];
#pragma unroll
  for (int mf = 0; mf < 2; ++mf)
#pragma unroll
    for (int nf = 0; nf < 12; ++nf) acc[mf][nf] = (f32x4)(0.0f);

  const size_t a_lane_off = (size_t)l15 * KK + l4 * 8;

  for (int st = 0; st < NSTEP; ++st) {
    const int k0 = st * 32;
    if (wave < 4) {
      const short* src = Aws + (size_t)(t0 + wave * 16) * KK + a_lane_off + k0;
      __builtin_amdgcn_global_load_lds(
          (const __attribute__((address_space(1))) unsigned int*)src,
          (__attribute__((address_space(3))) unsigned int*)(Atile + wave * 512),
          16, 0, 0);
    }
#pragma unroll
    for (int p = 0; p < 6; ++p) {
      int c = p * 8 + wave;
      const short* src = Btw + (size_t)(c * 16) * KK + a_lane_off + k0;
      __builtin_amdgcn_global_load_lds(
          (const __attribute__((address_space(1))) unsigned int*)src,
          (__attribute__((address_space(3))) unsigned int*)(Bt + c * 512),
          16, 0, 0);
    }
    __syncthreads();

    const bf16x8* Af = (const bf16x8*)Atile;
    const bf16x8* Bf = (const bf16x8*)Bt;
    bf16x8 a0 = Af[(wm * 2 + 0) * 64 + l4 * 16 + l15];
    bf16x8 a1 = Af[(wm * 2 + 1) * 64 + l4 * 16 + l15];
#pragma unroll
    for (int nf = 0; nf < 12; ++nf) {
      bf16x8 b = Bf[(wn * 12 + nf) * 64 + l4 * 16 + l15];
      acc[0][nf] = __builtin_amdgcn_mfma_f32_16x16x32_bf16(a0, b, acc[0][nf], 0, 0, 0);
      acc[1][nf] = __builtin_amdgcn_mfma_f32_16x16x32_bf16(a1, b, acc[1][nf], 0, 0, 0);
    }
    __syncthreads();
  }

  // ---- epilogue: tanh + embedding adds + LayerNorm stats
  float sp[2][4], sq[2][4];
#pragma unroll
  for (int mf = 0; mf < 2; ++mf)
#pragma unroll
    for (int r = 0; r < 4; ++r) { sp[mf][r] = 0.f; sq[mf][r] = 0.f; }

#pragma unroll
  for (int nf = 0; nf < 12; ++nf) {
    int n = wn * 192 + nf * 16 + l15;
    float bias = lin_b[n];
#pragma unroll
    for (int mf = 0; mf < 2; ++mf) {
#pragma unroll
      for (int r = 0; r < 4; ++r) {
        int row = wm * 32 + mf * 16 + l4 * 4 + r;
        float z = tanhf(acc[mf][nf][r] + bias);
        z += W_type[(size_t)tyl[row] * HH + n];
        z += W_order[(size_t)orl[row] * HH + n];
        z += W_seg[(size_t)sgl[row] * HH + n];
        acc[mf][nf][r] = z;
        sp[mf][r] += z;
        sq[mf][r] += z * z;
      }
    }
  }
#pragma unroll
  for (int m = 1; m < 16; m <<= 1) {
#pragma unroll
    for (int mf = 0; mf < 2; ++mf)
#pragma unroll
      for (int r = 0; r < 4; ++r) {
        sp[mf][r] += __shfl_xor(sp[mf][r], m, 64);
        sq[mf][r] += __shfl_xor(sq[mf][r], m, 64);
      }
  }
  if (l15 == 0) {
#pragma unroll
    for (int mf = 0; mf < 2; ++mf)
#pragma unroll
      for (int r = 0; r < 4; ++r) {
        int row = wm * 32 + mf * 16 + l4 * 4 + r;
        redS[wn][row] = sp[mf][r];
        redQ[wn][row] = sq[mf][r];
      }
  }
  __syncthreads();

  float mu[2][4], rs[2][4];
#pragma unroll
  for (int mf = 0; mf < 2; ++mf)
#pragma unroll
    for (int r = 0; r < 4; ++r) {
      int row = wm * 32 + mf * 16 + l4 * 4 + r;
      float s = redS[0][row] + redS[1][row] + redS[2][row] + redS[3][row];
      float q = redQ[0][row] + redQ[1][row] + redQ[2][row] + redQ[3][row];
      float m_ = s * (1.0f / 768.0f);
      float v_ = q * (1.0f / 768.0f) - m_ * m_;
      if (v_ < 0.f) v_ = 0.f;
      mu[mf][r] = m_;
      rs[mf][r] = rsqrtf(v_ + 1e-12f);
    }

  // ---- staged stores: 4 groups of 16 rows through LDS, contiguous out.
  // FULLY UNROLLED so acc[][] indices stay compile-time (rule #20: runtime
  // indexing demotes the whole accumulator array to scratch -> 5.7GB HBM
  // writeback observed in R2).
  float* Os = (float*)Bt;  // 48KB >= 16*768*4
#pragma unroll
  for (int g = 0; g < 4; ++g) {
    const int gw = g >> 1, gm = g & 1;
    __syncthreads();
    if (wm == gw) {
#pragma unroll
      for (int nf = 0; nf < 12; ++nf) {
        int n = wn * 192 + nf * 16 + l15;
        float gg = ln_g[n], be = ln_beta[n];
#pragma unroll
        for (int r = 0; r < 4; ++r) {
          int lr = l4 * 4 + r;
          Os[lr * HH + n] = (acc[gm][nf][r] - mu[gm][r]) * rs[gm][r] * gg + be;
        }
      }
    }
    __syncthreads();
    float* ob = out + (size_t)(t0 + g * 16) * HH;
#pragma unroll
    for (int q = 0; q < 6; ++q) {
      int idx4 = q * 512 + tid;
      ((f32x4*)ob)[idx4] = ((const f32x4*)Os)[idx4];
    }
  }
}

// =================== fallback (R1 kernel, ws-light) ===================
template <bool WS>
__global__ __launch_bounds__(512, 1) void ehr_fallback(
    const int* __restrict__ input_ids, const int* __restrict__ type_ids,
    const float* __restrict__ time_stamps, const float* __restrict__ ages,
    const int* __restrict__ visit_orders, const int* __restrict__ visit_segments,
    const float* __restrict__ W_word, const float* __restrict__ W_type,
    const float* __restrict__ W_order, const float* __restrict__ W_seg,
    const float* __restrict__ time_w, const float* __restrict__ time_phi,
    const float* __restrict__ age_w, const float* __restrict__ age_phi,
    const float* __restrict__ lin_W, const float* __restrict__ lin_b,
    const float* __restrict__ ln_g, const float* __restrict__ ln_beta,
    const short* __restrict__ bt_ws, float* __restrict__ out) {
  __shared__ short Bt[HH * 32];
  __shared__ short Atile[64 * 32];
  __shared__ float dtl[64], agel[64];
  __shared__ int idl[64], tyl[64], orl[64], sgl[64];
  __shared__ float tpar[128];
  __shared__ float redS[4][64], redQ[4][64];

  const int tid = threadIdx.x;
  const int t0 = blockIdx.x * 64;

  if (tid < 128) {
    int j = tid & 31;
    float v;
    if (tid < 32) v = time_w[j];
    else if (tid < 64) v = time_phi[j];
    else if (tid < 96) v = age_w[j];
    else v = age_phi[j];
    tpar[tid] = v;
  }
  if (tid < 64) {
    int t = t0 + tid;
    int s = t & (SS - 1);
    float tsv = time_stamps[t];
    dtl[tid] = (s == 0) ? 0.f : (tsv - time_stamps[t - 1]);
    agel[tid] = ages[t];
    idl[tid] = input_ids[t];
    tyl[tid] = type_ids[t];
    orl[tid] = visit_orders[t];
    sgl[tid] = visit_segments[t];
  }
  __syncthreads();

  const int lane = tid & 63, wave = tid >> 6;
  const int wm = wave >> 2, wn = wave & 3;
  const int l15 = lane & 15, l4 = lane >> 4;
  const int arow = tid >> 3, ac = tid & 7;
  const int myid = idl[arow];
  const float mydt = dtl[arow];
  const float myage = agel[arow];
  const float* wrow = W_word + (size_t)myid * HH;

  f32x4 acc[2][12];
#pragma unroll
  for (int mf = 0; mf < 2; ++mf)
#pragma unroll
    for (int nf = 0; nf < 12; ++nf) acc[mf][nf] = (f32x4)(0.0f);

  for (int st = 0; st < NSTEP; ++st) {
    const int k0 = st * 32;
    {
      int kg = k0 + ac * 4;
      bf16x4 w4;
      if (kg < HH) {
        const f32x4 v = *(const f32x4*)(wrow + kg);
        w4[0] = f2bf(v[0]); w4[1] = f2bf(v[1]);
        w4[2] = f2bf(v[2]); w4[3] = f2bf(v[3]);
      } else {
        int isAge = (kg >= HH + TT);
        int j = kg - (isAge ? (HH + TT) : HH);
        float x = isAge ? myage : mydt;
        int wof = isAge ? 64 : 0;
#pragma unroll
        for (int i = 0; i < 4; ++i)
          w4[i] = f2bf(sinf(x * tpar[wof + j + i] + tpar[wof + 32 + j + i]));
      }
      *(bf16x4*)(Atile + tid * 4) = w4;
    }
    if (WS) {
#pragma unroll
      for (int p = 0; p < 6; ++p) {
        int chunk = p * 8 + wave;
        short* ldst = Bt + chunk * 512;
        int n = chunk * 16 + (lane >> 2);
        int q = lane & 3;
        const short* src = bt_ws + (size_t)n * KK + k0 + q * 8;
        __builtin_amdgcn_global_load_lds(
            (const __attribute__((address_space(1))) unsigned int*)src,
            (__attribute__((address_space(3))) unsigned int*)ldst, 16, 0, 0);
      }
    } else {
#pragma unroll
      for (int i6 = 0; i6 < 6; ++i6) {
        int c = i6 * 512 + tid;
        int n = c >> 2, q = c & 3;
        int kb = k0 + q * 8;
        bf16x8 w8;
#pragma unroll
        for (int j = 0; j < 8; ++j) w8[j] = f2bf(lin_W[(size_t)(kb + j) * HH + n]);
        *(bf16x8*)(Bt + n * 32 + q * 8) = w8;
      }
    }
    __syncthreads();

    const bf16x8* Af = (const bf16x8*)Atile;
    const bf16x8* Bf = (const bf16x8*)Bt;
    bf16x8 a0 = Af[(wm * 32 + l15) * 4 + l4];
    bf16x8 a1 = Af[(wm * 32 + 16 + l15) * 4 + l4];
#pragma unroll
    for (int nf = 0; nf < 12; ++nf) {
      int n = wn * 192 + nf * 16 + l15;
      bf16x8 b = Bf[n * 4 + l4];
      acc[0][nf] = __builtin_amdgcn_mfma_f32_16x16x32_bf16(a0, b, acc[0][nf], 0, 0, 0);
      acc[1][nf] = __builtin_amdgcn_mfma_f32_16x16x32_bf16(a1, b, acc[1][nf], 0, 0, 0);
    }
    __syncthreads();
  }

  float sp[2][4], sq[2][4];
#pragma unroll
  for (int mf = 0; mf < 2; ++mf)
#pragma unroll
    for (int r = 0; r < 4; ++r) { sp[mf][r] = 0.f; sq[mf][r] = 0.f; }

#pragma unroll
  for (int nf = 0; nf < 12; ++nf) {
    int n = wn * 192 + nf * 16 + l15;
    float bias = lin_b[n];
#pragma unroll
    for (int mf = 0; mf < 2; ++mf) {
#pragma unroll
      for (int r = 0; r < 4; ++r) {
        int row = wm * 32 + mf * 16 + l4 * 4 + r;
        float z = tanhf(acc[mf][nf][r] + bias);
        z += W_type[(size_t)tyl[row] * HH + n];
        z += W_order[(size_t)orl[row] * HH + n];
        z += W_seg[(size_t)sgl[row] * HH + n];
        acc[mf][nf][r] = z;
        sp[mf][r] += z;
        sq[mf][r] += z * z;
      }
    }
  }
#pragma unroll
  for (int m = 1; m < 16; m <<= 1) {
#pragma unroll
    for (int mf = 0; mf < 2; ++mf)
#pragma unroll
      for (int r = 0; r < 4; ++r) {
        sp[mf][r] += __shfl_xor(sp[mf][r], m, 64);
        sq[mf][r] += __shfl_xor(sq[mf][r], m, 64);
      }
  }
  if (l15 == 0) {
#pragma unroll
    for (int mf = 0; mf < 2; ++mf)
#pragma unroll
      for (int r = 0; r < 4; ++r) {
        int row = wm * 32 + mf * 16 + l4 * 4 + r;
        redS[wn][row] = sp[mf][r];
        redQ[wn][row] = sq[mf][r];
      }
  }
  __syncthreads();

  float mu[2][4], rs[2][4];
#pragma unroll
  for (int mf = 0; mf < 2; ++mf)
#pragma unroll
    for (int r = 0; r < 4; ++r) {
      int row = wm * 32 + mf * 16 + l4 * 4 + r;
      float s = redS[0][row] + redS[1][row] + redS[2][row] + redS[3][row];
      float q = redQ[0][row] + redQ[1][row] + redQ[2][row] + redQ[3][row];
      float m_ = s * (1.0f / 768.0f);
      float v_ = q * (1.0f / 768.0f) - m_ * m_;
      if (v_ < 0.f) v_ = 0.f;
      mu[mf][r] = m_;
      rs[mf][r] = rsqrtf(v_ + 1e-12f);
    }

#pragma unroll
  for (int nf = 0; nf < 12; ++nf) {
    int n = wn * 192 + nf * 16 + l15;
    float g = ln_g[n], be = ln_beta[n];
#pragma unroll
    for (int mf = 0; mf < 2; ++mf) {
#pragma unroll
      for (int r = 0; r < 4; ++r) {
        int row = wm * 32 + mf * 16 + l4 * 4 + r;
        out[(size_t)(t0 + row) * HH + n] =
            (acc[mf][nf][r] - mu[mf][r]) * rs[mf][r] * g + be;
      }
    }
  }
}

extern "C" void kernel_launch(void* const* d_in, const int* in_sizes, int n_in,
                              void* d_out, int out_size, void* d_ws, size_t ws_size,
                              hipStream_t stream) {
  const int* input_ids = (const int*)d_in[0];
  const int* type_ids = (const int*)d_in[1];
  const float* time_stamps = (const float*)d_in[2];
  const float* ages = (const float*)d_in[3];
  const int* visit_orders = (const int*)d_in[4];
  const int* visit_segments = (const int*)d_in[5];
  const float* W_word = (const float*)d_in[6];
  const float* W_type = (const float*)d_in[7];
  const float* W_order = (const float*)d_in[8];
  const float* W_seg = (const float*)d_in[9];
  const float* time_w = (const float*)d_in[10];
  const float* time_phi = (const float*)d_in[11];
  const float* age_w = (const float*)d_in[12];
  const float* age_phi = (const float*)d_in[13];
  const float* lin_W = (const float*)d_in[14];
  const float* lin_b = (const float*)d_in[15];
  const float* ln_g = (const float*)d_in[16];
  const float* ln_beta = (const float*)d_in[17];
  float* out = (float*)d_out;

  const size_t a_bytes = (size_t)NTOK * KK * sizeof(short);   // ~109 MB
  const size_t bt_bytes = (size_t)HH * KK * sizeof(short);    // ~1.2 MB

  if (d_ws != nullptr && ws_size >= a_bytes + bt_bytes) {
    short* Aws = (short*)d_ws;
    short* Btw = (short*)((char*)d_ws + a_bytes);
    transpose_w_kernel<<<dim3((HH * KK + 255) / 256), dim3(256), 0, stream>>>(lin_W, Btw);
    gather_a_kernel<<<dim3(NTOK / 4), dim3(256), 0, stream>>>(
        input_ids, time_stamps, ages, W_word, time_w, time_phi, age_w, age_phi, Aws);
    ehr_gemm_kernel<<<dim3(NTOK / 64), dim3(512), 0, stream>>>(
        type_ids, visit_orders, visit_segments, W_type, W_order, W_seg,
        lin_b, ln_g, ln_beta, (const short*)Aws, (const short*)Btw, out);
  } else if (d_ws != nullptr && ws_size >= bt_bytes) {
    short* bt = (short*)d_ws;
    transpose_w_kernel<<<dim3((HH * KK + 255) / 256), dim3(256), 0, stream>>>(lin_W, bt);
    ehr_fallback<true><<<dim3(1024), dim3(512), 0, stream>>>(
        input_ids, type_ids, time_stamps, ages, visit_orders, visit_segments,
        W_word, W_type, W_order, W_seg, time_w, time_phi, age_w, age_phi,
        lin_W, lin_b, ln_g, ln_beta, (const short*)bt, out);
  } else {
    ehr_fallback<false><<<dim3(1024), dim3(512), 0, stream>>>(
        input_ids, type_ids, time_stamps, ages, visit_orders, visit_segments,
        W_word, W_type, W_order, W_seg, time_w, time_phi, age_w, age_phi,
        lin_W, lin_b, ln_g, ln_beta, nullptr, out);
  }
}

// Round 4
// 591.152 us; speedup vs baseline: 1.9774x; 1.2920x over previous
//
#include <hip/hip_runtime.h>
#include <hip/hip_bf16.h>
#include <math.h>
#include <stdint.h>

#define HH 768
#define TT 32
#define KK 832           // H + 2T
#define SS 2048
#define NSTEP 26         // KK / 32
#define NTOK 65536       // B*S
#define BM 32            // rows per block (keeps acc at 48 VGPR/thread)

typedef __attribute__((ext_vector_type(4))) float f32x4;
typedef __attribute__((ext_vector_type(8))) short bf16x8;
typedef __attribute__((ext_vector_type(4))) short bf16x4;

__device__ __forceinline__ short f2bf(float f) {
  union { float f; uint32_t u; } v; v.f = f;
  uint32_t u = v.u;
  return (short)((u + 0x7FFFu + ((u >> 16) & 1u)) >> 16);
}

// ---------------- transpose lin_W -> Btw[n][k] bf16 ----------------
__global__ void transpose_w_kernel(const float* __restrict__ lin_W,
                                   short* __restrict__ bt) {
  int i = blockIdx.x * 256 + threadIdx.x;
  if (i >= HH * KK) return;
  int n = i / KK;
  int k = i - n * KK;
  bt[i] = f2bf(lin_W[(size_t)k * HH + n]);
}

// ------------- gather kernel: build A[65536][832] bf16 -------------
__global__ __launch_bounds__(256) void gather_a_kernel(
    const int* __restrict__ input_ids, const float* __restrict__ ts,
    const float* __restrict__ ages, const float* __restrict__ W_word,
    const float* __restrict__ time_w, const float* __restrict__ time_phi,
    const float* __restrict__ age_w, const float* __restrict__ age_phi,
    short* __restrict__ Aws) {
  const int wave = threadIdx.x >> 6, lane = threadIdx.x & 63;
  const int t = blockIdx.x * 4 + wave;
  if (t >= NTOK) return;
  const float* wrow = W_word + (size_t)input_ids[t] * HH;
  const int s = t & (SS - 1);
  const float dt = (s == 0) ? 0.f : (ts[t] - ts[t - 1]);
  const float age = ages[t];
  short* dst = Aws + (size_t)t * KK;
#pragma unroll
  for (int c2 = 0; c2 < 2; ++c2) {
    int chunk = c2 * 64 + lane;
    if (chunk < 104) {
      int k = chunk * 8;
      bf16x8 v;
      if (k < HH) {
        f32x4 x0 = *(const f32x4*)(wrow + k);
        f32x4 x1 = *(const f32x4*)(wrow + k + 4);
        v[0] = f2bf(x0[0]); v[1] = f2bf(x0[1]); v[2] = f2bf(x0[2]); v[3] = f2bf(x0[3]);
        v[4] = f2bf(x1[0]); v[5] = f2bf(x1[1]); v[6] = f2bf(x1[2]); v[7] = f2bf(x1[3]);
      } else if (k < HH + TT) {
        int j = k - HH;
#pragma unroll
        for (int i = 0; i < 8; ++i)
          v[i] = f2bf(sinf(dt * time_w[j + i] + time_phi[j + i]));
      } else {
        int j = k - HH - TT;
#pragma unroll
        for (int i = 0; i < 8; ++i)
          v[i] = f2bf(sinf(age * age_w[j + i] + age_phi[j + i]));
      }
      *(bf16x8*)(dst + k) = v;
    }
  }
}

// ---------------- main GEMM + epilogue kernel (BM=32) ---------------
// LDS 16B-unit layouts (conflict-free ds_read_b128):
//   Atile: idx16 = panel*64 + kq*16 + rin   (panel = row>>4, 2 panels)
//   Bt:    idx16 = (n>>4)*64 + kq*16 + (n&15)
__global__ __launch_bounds__(512) void ehr_gemm_kernel(
    const int* __restrict__ type_ids, const int* __restrict__ visit_orders,
    const int* __restrict__ visit_segments, const float* __restrict__ W_type,
    const float* __restrict__ W_order, const float* __restrict__ W_seg,
    const float* __restrict__ lin_b, const float* __restrict__ ln_g,
    const float* __restrict__ ln_beta, const short* __restrict__ Aws,
    const short* __restrict__ Btw, float* __restrict__ out) {
  __shared__ short Bt[HH * 32];     // 48KB
  __shared__ short Atile[BM * 32];  // 2KB
  __shared__ int tyl[BM], orl[BM], sgl[BM];
  __shared__ float redS[4][BM], redQ[4][BM];

  const int tid = threadIdx.x;
  const int t0 = blockIdx.x * BM;
  if (tid < BM) {
    tyl[tid] = type_ids[t0 + tid];
    orl[tid] = visit_orders[t0 + tid];
    sgl[tid] = visit_segments[t0 + tid];
  }
  const int lane = tid & 63, wave = tid >> 6;
  const int wm = wave >> 2, wn = wave & 3;   // wm in {0,1}, wn in {0..3}
  const int l15 = lane & 15, l4 = lane >> 4;

  f32x4 acc[12];
#pragma unroll
  for (int nf = 0; nf < 12; ++nf) acc[nf] = (f32x4)(0.0f);

  const size_t a_lane_off = (size_t)l15 * KK + l4 * 8;

  for (int st = 0; st < NSTEP; ++st) {
    const int k0 = st * 32;
    // A: 2 chunks of 1KB, waves 0..1
    if (wave < 2) {
      const short* src = Aws + (size_t)(t0 + wave * 16) * KK + a_lane_off + k0;
      __builtin_amdgcn_global_load_lds(
          (const __attribute__((address_space(1))) unsigned int*)src,
          (__attribute__((address_space(3))) unsigned int*)(Atile + wave * 512),
          16, 0, 0);
    }
    // B: 48 chunks of 1KB, 6 per wave
#pragma unroll
    for (int p = 0; p < 6; ++p) {
      int c = p * 8 + wave;
      const short* src = Btw + (size_t)(c * 16) * KK + a_lane_off + k0;
      __builtin_amdgcn_global_load_lds(
          (const __attribute__((address_space(1))) unsigned int*)src,
          (__attribute__((address_space(3))) unsigned int*)(Bt + c * 512),
          16, 0, 0);
    }
    __syncthreads();

    const bf16x8* Af = (const bf16x8*)Atile;
    const bf16x8* Bf = (const bf16x8*)Bt;
    bf16x8 a = Af[wm * 64 + l4 * 16 + l15];
#pragma unroll
    for (int nf = 0; nf < 12; ++nf) {
      bf16x8 b = Bf[(wn * 12 + nf) * 64 + l4 * 16 + l15];
      acc[nf] = __builtin_amdgcn_mfma_f32_16x16x32_bf16(a, b, acc[nf], 0, 0, 0);
    }
    __syncthreads();
  }

  // ---- epilogue: tanh + embedding adds + LayerNorm stats
  float sp[4], sq[4];
#pragma unroll
  for (int r = 0; r < 4; ++r) { sp[r] = 0.f; sq[r] = 0.f; }

#pragma unroll
  for (int nf = 0; nf < 12; ++nf) {
    int n = wn * 192 + nf * 16 + l15;
    float bias = lin_b[n];
#pragma unroll
    for (int r = 0; r < 4; ++r) {
      int row = wm * 16 + l4 * 4 + r;
      float z = tanhf(acc[nf][r] + bias);
      z += W_type[(size_t)tyl[row] * HH + n];
      z += W_order[(size_t)orl[row] * HH + n];
      z += W_seg[(size_t)sgl[row] * HH + n];
      acc[nf][r] = z;
      sp[r] += z;
      sq[r] += z * z;
    }
  }
#pragma unroll
  for (int m = 1; m < 16; m <<= 1) {
#pragma unroll
    for (int r = 0; r < 4; ++r) {
      sp[r] += __shfl_xor(sp[r], m, 64);
      sq[r] += __shfl_xor(sq[r], m, 64);
    }
  }
  if (l15 == 0) {
#pragma unroll
    for (int r = 0; r < 4; ++r) {
      int row = wm * 16 + l4 * 4 + r;
      redS[wn][row] = sp[r];
      redQ[wn][row] = sq[r];
    }
  }
  __syncthreads();

  float mu[4], rs[4];
#pragma unroll
  for (int r = 0; r < 4; ++r) {
    int row = wm * 16 + l4 * 4 + r;
    float s = redS[0][row] + redS[1][row] + redS[2][row] + redS[3][row];
    float q = redQ[0][row] + redQ[1][row] + redQ[2][row] + redQ[3][row];
    float m_ = s * (1.0f / 768.0f);
    float v_ = q * (1.0f / 768.0f) - m_ * m_;
    if (v_ < 0.f) v_ = 0.f;
    mu[r] = m_;
    rs[r] = rsqrtf(v_ + 1e-12f);
  }

  // ---- staged stores: 2 groups of 16 rows through LDS, contiguous out.
  // Fully unrolled; all acc indices compile-time (rule #20).
  float* Os = (float*)Bt;  // 48KB == 16*768*4
#pragma unroll
  for (int g = 0; g < 2; ++g) {
    __syncthreads();
    if (wm == g) {
#pragma unroll
      for (int nf = 0; nf < 12; ++nf) {
        int n = wn * 192 + nf * 16 + l15;
        float gg = ln_g[n], be = ln_beta[n];
#pragma unroll
        for (int r = 0; r < 4; ++r) {
          int lr = l4 * 4 + r;
          Os[lr * HH + n] = (acc[nf][r] - mu[r]) * rs[r] * gg + be;
        }
      }
    }
    __syncthreads();
    float* ob = out + (size_t)(t0 + g * 16) * HH;
#pragma unroll
    for (int q = 0; q < 6; ++q) {
      int idx4 = q * 512 + tid;
      ((f32x4*)ob)[idx4] = ((const f32x4*)Os)[idx4];
    }
  }
}

// =================== fallback (R1 kernel, ws-light) ===================
template <bool WS>
__global__ __launch_bounds__(512, 1) void ehr_fallback(
    const int* __restrict__ input_ids, const int* __restrict__ type_ids,
    const float* __restrict__ time_stamps, const float* __restrict__ ages,
    const int* __restrict__ visit_orders, const int* __restrict__ visit_segments,
    const float* __restrict__ W_word, const float* __restrict__ W_type,
    const float* __restrict__ W_order, const float* __restrict__ W_seg,
    const float* __restrict__ time_w, const float* __restrict__ time_phi,
    const float* __restrict__ age_w, const float* __restrict__ age_phi,
    const float* __restrict__ lin_W, const float* __restrict__ lin_b,
    const float* __restrict__ ln_g, const float* __restrict__ ln_beta,
    const short* __restrict__ bt_ws, float* __restrict__ out) {
  __shared__ short Bt[HH * 32];
  __shared__ short Atile[64 * 32];
  __shared__ float dtl[64], agel[64];
  __shared__ int idl[64], tyl[64], orl[64], sgl[64];
  __shared__ float tpar[128];
  __shared__ float redS[4][64], redQ[4][64];

  const int tid = threadIdx.x;
  const int t0 = blockIdx.x * 64;

  if (tid < 128) {
    int j = tid & 31;
    float v;
    if (tid < 32) v = time_w[j];
    else if (tid < 64) v = time_phi[j];
    else if (tid < 96) v = age_w[j];
    else v = age_phi[j];
    tpar[tid] = v;
  }
  if (tid < 64) {
    int t = t0 + tid;
    int s = t & (SS - 1);
    float tsv = time_stamps[t];
    dtl[tid] = (s == 0) ? 0.f : (tsv - time_stamps[t - 1]);
    agel[tid] = ages[t];
    idl[tid] = input_ids[t];
    tyl[tid] = type_ids[t];
    orl[tid] = visit_orders[t];
    sgl[tid] = visit_segments[t];
  }
  __syncthreads();

  const int lane = tid & 63, wave = tid >> 6;
  const int wm = wave >> 2, wn = wave & 3;
  const int l15 = lane & 15, l4 = lane >> 4;
  const int arow = tid >> 3, ac = tid & 7;
  const int myid = idl[arow];
  const float mydt = dtl[arow];
  const float myage = agel[arow];
  const float* wrow = W_word + (size_t)myid * HH;

  f32x4 acc[2][12];
#pragma unroll
  for (int mf = 0; mf < 2; ++mf)
#pragma unroll
    for (int nf = 0; nf < 12; ++nf) acc[mf][nf] = (f32x4)(0.0f);

  for (int st = 0; st < NSTEP; ++st) {
    const int k0 = st * 32;
    {
      int kg = k0 + ac * 4;
      bf16x4 w4;
      if (kg < HH) {
        const f32x4 v = *(const f32x4*)(wrow + kg);
        w4[0] = f2bf(v[0]); w4[1] = f2bf(v[1]);
        w4[2] = f2bf(v[2]); w4[3] = f2bf(v[3]);
      } else {
        int isAge = (kg >= HH + TT);
        int j = kg - (isAge ? (HH + TT) : HH);
        float x = isAge ? myage : mydt;
        int wof = isAge ? 64 : 0;
#pragma unroll
        for (int i = 0; i < 4; ++i)
          w4[i] = f2bf(sinf(x * tpar[wof + j + i] + tpar[wof + 32 + j + i]));
      }
      *(bf16x4*)(Atile + tid * 4) = w4;
    }
    if (WS) {
#pragma unroll
      for (int p = 0; p < 6; ++p) {
        int chunk = p * 8 + wave;
        short* ldst = Bt + chunk * 512;
        int n = chunk * 16 + (lane >> 2);
        int q = lane & 3;
        const short* src = bt_ws + (size_t)n * KK + k0 + q * 8;
        __builtin_amdgcn_global_load_lds(
            (const __attribute__((address_space(1))) unsigned int*)src,
            (__attribute__((address_space(3))) unsigned int*)ldst, 16, 0, 0);
      }
    } else {
#pragma unroll
      for (int i6 = 0; i6 < 6; ++i6) {
        int c = i6 * 512 + tid;
        int n = c >> 2, q = c & 3;
        int kb = k0 + q * 8;
        bf16x8 w8;
#pragma unroll
        for (int j = 0; j < 8; ++j) w8[j] = f2bf(lin_W[(size_t)(kb + j) * HH + n]);
        *(bf16x8*)(Bt + n * 32 + q * 8) = w8;
      }
    }
    __syncthreads();

    const bf16x8* Af = (const bf16x8*)Atile;
    const bf16x8* Bf = (const bf16x8*)Bt;
    bf16x8 a0 = Af[(wm * 32 + l15) * 4 + l4];
    bf16x8 a1 = Af[(wm * 32 + 16 + l15) * 4 + l4];
#pragma unroll
    for (int nf = 0; nf < 12; ++nf) {
      int n = wn * 192 + nf * 16 + l15;
      bf16x8 b = Bf[n * 4 + l4];
      acc[0][nf] = __builtin_amdgcn_mfma_f32_16x16x32_bf16(a0, b, acc[0][nf], 0, 0, 0);
      acc[1][nf] = __builtin_amdgcn_mfma_f32_16x16x32_bf16(a1, b, acc[1][nf], 0, 0, 0);
    }
    __syncthreads();
  }

  float sp[2][4], sq[2][4];
#pragma unroll
  for (int mf = 0; mf < 2; ++mf)
#pragma unroll
    for (int r = 0; r < 4; ++r) { sp[mf][r] = 0.f; sq[mf][r] = 0.f; }

#pragma unroll
  for (int nf = 0; nf < 12; ++nf) {
    int n = wn * 192 + nf * 16 + l15;
    float bias = lin_b[n];
#pragma unroll
    for (int mf = 0; mf < 2; ++mf) {
#pragma unroll
      for (int r = 0; r < 4; ++r) {
        int row = wm * 32 + mf * 16 + l4 * 4 + r;
        float z = tanhf(acc[mf][nf][r] + bias);
        z += W_type[(size_t)tyl[row] * HH + n];
        z += W_order[(size_t)orl[row] * HH + n];
        z += W_seg[(size_t)sgl[row] * HH + n];
        acc[mf][nf][r] = z;
        sp[mf][r] += z;
        sq[mf][r] += z * z;
      }
    }
  }
#pragma unroll
  for (int m = 1; m < 16; m <<= 1) {
#pragma unroll
    for (int mf = 0; mf < 2; ++mf)
#pragma unroll
      for (int r = 0; r < 4; ++r) {
        sp[mf][r] += __shfl_xor(sp[mf][r], m, 64);
        sq[mf][r] += __shfl_xor(sq[mf][r], m, 64);
      }
  }
  if (l15 == 0) {
#pragma unroll
    for (int mf = 0; mf < 2; ++mf)
#pragma unroll
      for (int r = 0; r < 4; ++r) {
        int row = wm * 32 + mf * 16 + l4 * 4 + r;
        redS[wn][row] = sp[mf][r];
        redQ[wn][row] = sq[mf][r];
      }
  }
  __syncthreads();

  float mu[2][4], rs[2][4];
#pragma unroll
  for (int mf = 0; mf < 2; ++mf)
#pragma unroll
    for (int r = 0; r < 4; ++r) {
      int row = wm * 32 + mf * 16 + l4 * 4 + r;
      float s = redS[0][row] + redS[1][row] + redS[2][row] + redS[3][row];
      float q = redQ[0][row] + redQ[1][row] + redQ[2][row] + redQ[3][row];
      float m_ = s * (1.0f / 768.0f);
      float v_ = q * (1.0f / 768.0f) - m_ * m_;
      if (v_ < 0.f) v_ = 0.f;
      mu[mf][r] = m_;
      rs[mf][r] = rsqrtf(v_ + 1e-12f);
    }

#pragma unroll
  for (int nf = 0; nf < 12; ++nf) {
    int n = wn * 192 + nf * 16 + l15;
    float g = ln_g[n], be = ln_beta[n];
#pragma unroll
    for (int mf = 0; mf < 2; ++mf) {
#pragma unroll
      for (int r = 0; r < 4; ++r) {
        int row = wm * 32 + mf * 16 + l4 * 4 + r;
        out[(size_t)(t0 + row) * HH + n] =
            (acc[mf][nf][r] - mu[mf][r]) * rs[mf][r] * g + be;
      }
    }
  }
}

extern "C" void kernel_launch(void* const* d_in, const int* in_sizes, int n_in,
                              void* d_out, int out_size, void* d_ws, size_t ws_size,
                              hipStream_t stream) {
  const int* input_ids = (const int*)d_in[0];
  const int* type_ids = (const int*)d_in[1];
  const float* time_stamps = (const float*)d_in[2];
  const float* ages = (const float*)d_in[3];
  const int* visit_orders = (const int*)d_in[4];
  const int* visit_segments = (const int*)d_in[5];
  const float* W_word = (const float*)d_in[6];
  const float* W_type = (const float*)d_in[7];
  const float* W_order = (const float*)d_in[8];
  const float* W_seg = (const float*)d_in[9];
  const float* time_w = (const float*)d_in[10];
  const float* time_phi = (const float*)d_in[11];
  const float* age_w = (const float*)d_in[12];
  const float* age_phi = (const float*)d_in[13];
  const float* lin_W = (const float*)d_in[14];
  const float* lin_b = (const float*)d_in[15];
  const float* ln_g = (const float*)d_in[16];
  const float* ln_beta = (const float*)d_in[17];
  float* out = (float*)d_out;

  const size_t a_bytes = (size_t)NTOK * KK * sizeof(short);   // ~109 MB
  const size_t bt_bytes = (size_t)HH * KK * sizeof(short);    // ~1.2 MB

  if (d_ws != nullptr && ws_size >= a_bytes + bt_bytes) {
    short* Aws = (short*)d_ws;
    short* Btw = (short*)((char*)d_ws + a_bytes);
    transpose_w_kernel<<<dim3((HH * KK + 255) / 256), dim3(256), 0, stream>>>(lin_W, Btw);
    gather_a_kernel<<<dim3(NTOK / 4), dim3(256), 0, stream>>>(
        input_ids, time_stamps, ages, W_word, time_w, time_phi, age_w, age_phi, Aws);
    ehr_gemm_kernel<<<dim3(NTOK / BM), dim3(512), 0, stream>>>(
        type_ids, visit_orders, visit_segments, W_type, W_order, W_seg,
        lin_b, ln_g, ln_beta, (const short*)Aws, (const short*)Btw, out);
  } else if (d_ws != nullptr && ws_size >= bt_bytes) {
    short* bt = (short*)d_ws;
    transpose_w_kernel<<<dim3((HH * KK + 255) / 256), dim3(256), 0, stream>>>(lin_W, bt);
    ehr_fallback<true><<<dim3(1024), dim3(512), 0, stream>>>(
        input_ids, type_ids, time_stamps, ages, visit_orders, visit_segments,
        W_word, W_type, W_order, W_seg, time_w, time_phi, age_w, age_phi,
        lin_W, lin_b, ln_g, ln_beta, (const short*)bt, out);
  } else {
    ehr_fallback<false><<<dim3(1024), dim3(512), 0, stream>>>(
        input_ids, type_ids, time_stamps, ages, visit_orders, visit_segments,
        W_word, W_type, W_order, W_seg, time_w, time_phi, age_w, age_phi,
        lin_W, lin_b, ln_g, ln_beta, nullptr, out);
  }
}